// Round 7
// baseline (77.192 us; speedup 1.0000x reference)
//
#include <hip/hip_runtime.h>

// speed[n,d] = sum_{f,m} Cont[f] * exp(-||P[n]-S[f,m]||^2) * V[f,m,d]
//
// Full exponent in the MFMA:  D[n][e] = -K1*d2 = K2*(p.s) - K1*|p|^2 - K1*|s|^2
// (K1=log2e, K2=2K1), via 32x32x16 bf16 with hi/lo-compensated splits.
// Slot table (A = point fragment, B = support fragment):
//   k0-2 : qh_{xyz} * sh_{xyz}     k3-5 : ql_{xyz} * sh_{xyz}
//   k6-8 : qh_{xyz} * sl_{xyz}     k9-10: ONE * yh, ONE * yl
//   k12-13: xh*ONE, xl*ONE         k11, k14, k15: zero
// where sh+sl ~= K2*s, qh+ql ~= p, xh+xl ~= -K1*|p|^2, yh+yl ~= -K1*|s|^2.
// (ql*sl cross terms dropped: rel 2^-16 — negligible.)  w = exp2(D) <= ~1,
// term = w * Cont[f] * v[e]; Cont is wave-uniform per tile (16 tiles per f).
// Scratch = B fragments only = 128 KB (the R2-proven d_ws footprint; R4-R6's
// 192 KB overflowed ws — error magnitude matched the overflow data).

typedef short  bf16x8 __attribute__((ext_vector_type(8)));
typedef float  f32x16 __attribute__((ext_vector_type(16)));
typedef float  v2f    __attribute__((ext_vector_type(2)));

#define K1f 1.4426950408889634f
#define K2f 2.8853900817779268f

constexpr int N_PTS  = 65536;
constexpr int MM     = 512;
constexpr int FM     = 4096;            // F*M entries
constexpr int SPLITS = 4;               // e-splits (atomic contenders per addr)
constexpr int ETILES = FM / 32;         // 128 e-tiles of 32 entries
constexpr int TPS    = ETILES / SPLITS; // 32 tiles per split

__device__ __forceinline__ unsigned short bf16r(float f) {   // RNE f32->bf16
  unsigned u = __float_as_uint(f);
  return (unsigned short)((u + 0x7FFFu + ((u >> 16) & 1u)) >> 16);
}
__device__ __forceinline__ float bf2f(unsigned short h) {
  return __uint_as_float(((unsigned)h) << 16);
}

__global__ __launch_bounds__(256) void pack_kernel(
    const float* __restrict__ supp_pts, unsigned short* __restrict__ bfrags) {
  int e = blockIdx.x * blockDim.x + threadIdx.x;
  if (e >= FM) return;
  float sx = supp_pts[e * 3 + 0];
  float sy = supp_pts[e * 3 + 1];
  float sz = supp_pts[e * 3 + 2];
  float tx = K2f * sx, ty = K2f * sy, tz = K2f * sz;
  unsigned short shx = bf16r(tx), shy = bf16r(ty), shz = bf16r(tz);
  unsigned short slx = bf16r(tx - bf2f(shx));
  unsigned short sly = bf16r(ty - bf2f(shy));
  unsigned short slz = bf16r(tz - bf2f(shz));
  float ye = -K1f * (sx * sx + sy * sy + sz * sz);
  unsigned short yh = bf16r(ye);
  unsigned short yl = bf16r(ye - bf2f(yh));
  const unsigned short ONE = 0x3F80;    // bf16 1.0 (exact)

  int t = e >> 5, c = e & 31;
  unsigned short* p0 = bfrags + (size_t)(t * 64 + c) * 8;        // k0-7 half
  p0[0] = shx; p0[1] = shy; p0[2] = shz; p0[3] = shx;
  p0[4] = shy; p0[5] = shz; p0[6] = slx; p0[7] = sly;
  unsigned short* p1 = bfrags + (size_t)(t * 64 + 32 + c) * 8;   // k8-15 half
  p1[0] = slz; p1[1] = yh;  p1[2] = yl;  p1[3] = 0;
  p1[4] = ONE; p1[5] = ONE; p1[6] = 0;   p1[7] = 0;
}

__global__ __launch_bounds__(256) void speed_kernel(
    const float* __restrict__ Points, const bf16x8* __restrict__ bfrags,
    const float* __restrict__ supp_vec, const float* __restrict__ Cont,
    float* __restrict__ out) {
  const int tid   = threadIdx.x;
  const int l     = tid & 63;
  const int wave  = tid >> 6;
  const int half  = l >> 5;
  const int c     = l & 31;
  const int split = blockIdx.x & (SPLITS - 1);
  const int nblk  = blockIdx.x / SPLITS;
  const int n_base = nblk * 128 + wave * 32;

  // ---- A-fragment: this wave's 32 points, hi/lo split ----
  const int n = n_base + c;
  float x = Points[n * 3 + 0];
  float y = Points[n * 3 + 1];
  float z = Points[n * 3 + 2];
  float e1 = -K1f * (x * x + y * y + z * z);
  unsigned short qhx = bf16r(x), qhy = bf16r(y), qhz = bf16r(z);
  unsigned short qlx = bf16r(x - bf2f(qhx));
  unsigned short qly = bf16r(y - bf2f(qhy));
  unsigned short qlz = bf16r(z - bf2f(qhz));
  unsigned short xh  = bf16r(e1);
  unsigned short xl  = bf16r(e1 - bf2f(xh));
  const short ONE = (short)0x3F80;

  bf16x8 af;
  if (half == 0) {
    af = (bf16x8){(short)qhx, (short)qhy, (short)qhz, (short)qlx,
                  (short)qly, (short)qlz, (short)qhx, (short)qhy};
  } else {
    af = (bf16x8){(short)qhz, ONE, ONE, 0, (short)xh, (short)xl, 0, 0};
  }

  f32x16 zc = {};                 // zero C operand
  v2f accx[8] = {}, accy[8] = {}, accz[8] = {};

  const int tbase = split * TPS;

#pragma unroll 2
  for (int t = 0; t < TPS; ++t) {
    const int tt = tbase + t;
    bf16x8 bf = bfrags[tt * 64 + l];
    float cont = Cont[tt >> 4];                 // wave-uniform -> s_load
    const int e = tt * 32 + c;
    float cvx = cont * supp_vec[e * 3 + 0];
    float cvy = cont * supp_vec[e * 3 + 1];
    float cvz = cont * supp_vec[e * 3 + 2];

    f32x16 D = __builtin_amdgcn_mfma_f32_32x32x16_bf16(af, bf, zc, 0, 0, 0);

    float w[16];
#pragma unroll
    for (int r = 0; r < 16; ++r) w[r] = __builtin_amdgcn_exp2f(D[r]);

    v2f vx = {cvx, cvx}, vy = {cvy, cvy}, vz = {cvz, cvz};
#pragma unroll
    for (int p = 0; p < 8; ++p) {
      v2f wp = {w[2 * p], w[2 * p + 1]};
      accx[p] = __builtin_elementwise_fma(wp, vx, accx[p]);
      accy[p] = __builtin_elementwise_fma(wp, vy, accy[p]);
      accz[p] = __builtin_elementwise_fma(wp, vz, accz[p]);
    }
  }

  // ---- Butterfly-reduce over the 32 e-lanes (masks <=16 stay in-half) ----
#pragma unroll
  for (int p = 0; p < 8; ++p) {
#pragma unroll
    for (int m = 1; m <= 16; m <<= 1) {
      float t0;
      t0 = accx[p].x; accx[p].x = t0 + __shfl_xor(t0, m);
      t0 = accx[p].y; accx[p].y = t0 + __shfl_xor(t0, m);
      t0 = accy[p].x; accy[p].x = t0 + __shfl_xor(t0, m);
      t0 = accy[p].y; accy[p].y = t0 + __shfl_xor(t0, m);
      t0 = accz[p].x; accz[p].x = t0 + __shfl_xor(t0, m);
      t0 = accz[p].y; accz[p].y = t0 + __shfl_xor(t0, m);
    }
  }

  // ---- One lane per half writes its 16 rows (SPLITS contenders/addr) ----
  if (c == 0) {
#pragma unroll
    for (int r = 0; r < 16; ++r) {
      int nn = n_base + (r & 3) + 8 * (r >> 2) + 4 * half;
      float fx = (r & 1) ? accx[r >> 1].y : accx[r >> 1].x;
      float fy = (r & 1) ? accy[r >> 1].y : accy[r >> 1].x;
      float fz = (r & 1) ? accz[r >> 1].y : accz[r >> 1].x;
      unsafeAtomicAdd(&out[nn * 3 + 0], fx);
      unsafeAtomicAdd(&out[nn * 3 + 1], fy);
      unsafeAtomicAdd(&out[nn * 3 + 2], fz);
    }
  }
}

extern "C" void kernel_launch(void* const* d_in, const int* in_sizes, int n_in,
                              void* d_out, int out_size, void* d_ws, size_t ws_size,
                              hipStream_t stream) {
  const float* Points   = (const float*)d_in[0];
  const float* supp_pts = (const float*)d_in[1];
  const float* supp_vec = (const float*)d_in[2];
  const float* Cont     = (const float*)d_in[3];
  float* out = (float*)d_out;

  unsigned short* bfrags = (unsigned short*)d_ws;   // 128 KB total, nothing else

  (void)hipMemsetAsync(d_out, 0, (size_t)out_size * sizeof(float), stream);
  pack_kernel<<<FM / 256, 256, 0, stream>>>(supp_pts, bfrags);
  speed_kernel<<<(N_PTS / 128) * SPLITS, 256, 0, stream>>>(
      Points, (const bf16x8*)bfrags, supp_vec, Cont, out);
}

// Round 8
// 64.623 us; speedup vs baseline: 1.1945x; 1.1945x over previous
//
#include <hip/hip_runtime.h>

// speed[n,d] = sum_{f,m} Cont[f] * exp(-||P[n]-S[f,m]||^2) * V[f,m,d]
//
// Two chained MFMAs per 32x32-tile:
//  MFMA1: D1[e][n] = -K1*d2(n,e)  (A=support frag, B=point frag; same slot
//         pairing as R7 which passed, operands swapped so cols = n)
//  elementwise: w = exp2(D1)  (16 regs), pack to bf16 pairs via v_perm
//  MFMA2: D2[d][n] += cv[d][e] * w[e][n]  over e=0..31 (2 MFMAs, K=16 each),
//         accumulating in C across ALL tiles -> no per-tile VALU accumulation.
// w reg r at lane l holds e = (r&3)+8*(r>>2)+4*(l>>5) (m74/m101 C/D map,
// R7-validated). Hence B2 slot (h=l>>5, j) holds e_a = (j&3)+8*(j>>2)+4h
// (frag a: regs 0-7) / e_a+16 (frag b: regs 8-15). pack_kernel writes
// cv = Cont*v into A2 at exactly those (h,j) slots. D2 valid rows: d=0,1,2
// at half 0, regs 0-2; col = n = lane&31.
// ws budget (<=128 KB proven): A1-half0 frags 64K | half1 compact 32K | A2 24K.

typedef short  bf16x8 __attribute__((ext_vector_type(8)));
typedef float  f32x16 __attribute__((ext_vector_type(16)));

#define K1f 1.4426950408889634f
#define K2f 2.8853900817779268f

constexpr int N_PTS  = 65536;
constexpr int MM     = 512;
constexpr int FM     = 4096;
constexpr int SPLITS = 4;
constexpr int ETILES = FM / 32;          // 128 tiles
constexpr int TPS    = ETILES / SPLITS;  // 32 tiles per block
constexpr size_t BUFA_OFF = 0;           // 4096 * 16B = 64 KB
constexpr size_t BUFB_OFF = 64 * 1024;   // 4096 *  8B = 32 KB
constexpr size_t A2_OFF   = 96 * 1024;   // 128*2*2*24 shorts = 24 KB

__device__ __forceinline__ unsigned short bf16r(float f) {   // RNE f32->bf16
  unsigned u = __float_as_uint(f);
  return (unsigned short)((u + 0x7FFFu + ((u >> 16) & 1u)) >> 16);
}
__device__ __forceinline__ float bf2f(unsigned short h) {
  return __uint_as_float(((unsigned)h) << 16);
}

union FragU { uint4 u4; bf16x8 bf; };

__global__ __launch_bounds__(256) void pack_kernel(
    const float* __restrict__ supp_pts, const float* __restrict__ supp_vec,
    const float* __restrict__ Cont, char* __restrict__ ws) {
  int e = blockIdx.x * blockDim.x + threadIdx.x;
  if (e >= FM) return;
  float sx = supp_pts[e * 3 + 0];
  float sy = supp_pts[e * 3 + 1];
  float sz = supp_pts[e * 3 + 2];
  float tx = K2f * sx, ty = K2f * sy, tz = K2f * sz;
  unsigned short shx = bf16r(tx), shy = bf16r(ty), shz = bf16r(tz);
  unsigned short slx = bf16r(tx - bf2f(shx));
  unsigned short sly = bf16r(ty - bf2f(shy));
  unsigned short slz = bf16r(tz - bf2f(shz));
  float ye = -K1f * (sx * sx + sy * sy + sz * sz);
  unsigned short yh = bf16r(ye);
  unsigned short yl = bf16r(ye - bf2f(yh));

  // A1 half0 fragment (ready to load as 16B): pairs with af half0
  // [qhx,qhy,qhz,qlx,qly,qlz,qhx,qhy]
  unsigned short* pa = (unsigned short*)(ws + BUFA_OFF) + (size_t)e * 8;
  pa[0] = shx; pa[1] = shy; pa[2] = shz; pa[3] = shx;
  pa[4] = shy; pa[5] = shz; pa[6] = slx; pa[7] = sly;
  // A1 half1 compact (8B): [slz, yh, yl, 0]; consts appended in-kernel
  unsigned short* pb = (unsigned short*)(ws + BUFB_OFF) + (size_t)e * 4;
  pb[0] = slz; pb[1] = yh; pb[2] = yl; pb[3] = 0;

  // A2: cv[d][e] at slot (t, frag, h, d, j) with e = (j&3)+8*(j>>2)+4h+16*frag
  int f = e >> 9;                          // e / MM, MM=512
  float cf = Cont[f];
  unsigned short cv0 = bf16r(cf * supp_vec[e * 3 + 0]);
  unsigned short cv1 = bf16r(cf * supp_vec[e * 3 + 1]);
  unsigned short cv2 = bf16r(cf * supp_vec[e * 3 + 2]);
  int t = e >> 5, el = e & 31;
  int frag = el >> 4, el16 = el & 15;
  int h = (el16 >> 2) & 1;
  int j = (el16 & 3) + 4 * (el16 >> 3);
  unsigned short* a2 = (unsigned short*)(ws + A2_OFF) +
                       (size_t)(((t * 2 + frag) * 2 + h) * 24 + j);
  a2[0] = cv0; a2[8] = cv1; a2[16] = cv2;   // d*8 + j
}

__global__ __launch_bounds__(256) void speed_kernel(
    const float* __restrict__ Points, const char* __restrict__ ws,
    float* __restrict__ out) {
  const int tid   = threadIdx.x;
  const int l     = tid & 63;
  const int wave  = tid >> 6;
  const int half  = l >> 5;
  const int c     = l & 31;
  const int split = blockIdx.x & (SPLITS - 1);
  const int nblk  = blockIdx.x / SPLITS;
  const int n_base = nblk * 128 + wave * 32;

  const uint4*  bufA = (const uint4*)(ws + BUFA_OFF);
  const uint2*  bufB = (const uint2*)(ws + BUFB_OFF);
  const bf16x8* A2   = (const bf16x8*)(ws + A2_OFF);  // 16B units; (t,frag,h) stride 3

  // ---- point fragment (B operand of MFMA1), same content as R7's af ----
  const int n = n_base + c;
  float x = Points[n * 3 + 0];
  float y = Points[n * 3 + 1];
  float z = Points[n * 3 + 2];
  float e1 = -K1f * (x * x + y * y + z * z);
  unsigned short qhx = bf16r(x), qhy = bf16r(y), qhz = bf16r(z);
  unsigned short qlx = bf16r(x - bf2f(qhx));
  unsigned short qly = bf16r(y - bf2f(qhy));
  unsigned short qlz = bf16r(z - bf2f(qhz));
  unsigned short xh  = bf16r(e1);
  unsigned short xl  = bf16r(e1 - bf2f(xh));
  const short ONE = (short)0x3F80;

  bf16x8 af;
  if (half == 0) {
    af = (bf16x8){(short)qhx, (short)qhy, (short)qhz, (short)qlx,
                  (short)qly, (short)qlz, (short)qhx, (short)qhy};
  } else {
    af = (bf16x8){(short)qhz, ONE, ONE, 0, (short)xh, (short)xl, 0, 0};
  }

  f32x16 zc   = {};   // C=0 for MFMA1
  f32x16 acc2 = {};   // D2 accumulator, carried across all tiles

  const int tbase = split * TPS;

#pragma unroll 2
  for (int t = 0; t < TPS; ++t) {
    const int tt = tbase + t;

    // A1 fragment: half0 direct 16B; half1 compact 8B + constants
    FragU fa;
    if (half == 0) {
      fa.u4 = bufA[tt * 32 + c];
    } else {
      uint2 tb = bufB[tt * 32 + c];
      fa.u4 = make_uint4(tb.x, tb.y, 0x3F803F80u, 0u);
    }

    f32x16 D1 = __builtin_amdgcn_mfma_f32_32x32x16_bf16(fa.bf, af, zc, 0, 0, 0);

    float w[16];
#pragma unroll
    for (int r = 0; r < 16; ++r) w[r] = __builtin_amdgcn_exp2f(D1[r]);

    // pack consecutive-reg pairs to bf16 (truncation): dword m = (w[2m],w[2m+1])
    unsigned p[8];
#pragma unroll
    for (int m = 0; m < 8; ++m)
      p[m] = __builtin_amdgcn_perm(__float_as_uint(w[2 * m + 1]),
                                   __float_as_uint(w[2 * m]), 0x07060302u);
    FragU b2a, b2b;
    b2a.u4 = make_uint4(p[0], p[1], p[2], p[3]);
    b2b.u4 = make_uint4(p[4], p[5], p[6], p[7]);

    bf16x8 a2a = {}, a2b = {};
    if (c < 3) {                         // rows d=0..2; other rows zero
      a2a = A2[((tt * 2 + 0) * 2 + half) * 3 + c];
      a2b = A2[((tt * 2 + 1) * 2 + half) * 3 + c];
    }

    acc2 = __builtin_amdgcn_mfma_f32_32x32x16_bf16(a2a, b2a.bf, acc2, 0, 0, 0);
    acc2 = __builtin_amdgcn_mfma_f32_32x32x16_bf16(a2b, b2b.bf, acc2, 0, 0, 0);
  }

  // D2 rows 0..2 (= d) live at half 0, regs 0..2; col = n = lane&31.
  if (half == 0) {
    const int nn = n_base + c;
    unsafeAtomicAdd(&out[nn * 3 + 0], acc2[0]);
    unsafeAtomicAdd(&out[nn * 3 + 1], acc2[1]);
    unsafeAtomicAdd(&out[nn * 3 + 2], acc2[2]);
  }
}

extern "C" void kernel_launch(void* const* d_in, const int* in_sizes, int n_in,
                              void* d_out, int out_size, void* d_ws, size_t ws_size,
                              hipStream_t stream) {
  const float* Points   = (const float*)d_in[0];
  const float* supp_pts = (const float*)d_in[1];
  const float* supp_vec = (const float*)d_in[2];
  const float* Cont     = (const float*)d_in[3];
  float* out = (float*)d_out;
  char* ws = (char*)d_ws;    // 120 KB used

  (void)hipMemsetAsync(d_out, 0, (size_t)out_size * sizeof(float), stream);
  pack_kernel<<<FM / 256, 256, 0, stream>>>(supp_pts, supp_vec, Cont, ws);
  speed_kernel<<<(N_PTS / 128) * SPLITS, 256, 0, stream>>>(Points, ws, out);
}

// Round 9
// 52.551 us; speedup vs baseline: 1.4689x; 1.2297x over previous
//
#include <hip/hip_runtime.h>

// speed[n,d] = sum_{f,m} Cont[f] * exp(-||P[n]-S[f,m]||^2) * V[f,m,d]
//
// Two chained MFMAs per 32x32-tile (R8-validated layouts, leaner dataflow):
//  MFMA1: D1[e][n] = -K1*d2(n,e)  (A=support frag, B=point frag)
//  fused: b2 dword m = bf16pack(exp2(D1[2m]), exp2(D1[2m+1]))  (no w[] array)
//  MFMA2: D2[d][n] += cv[d][e] * w[e][n], acc carried in C across all tiles.
// w reg r at lane l holds e=(r&3)+8*(r>>2)+4*(l>>5); A2 slot (h,j) holds
// e=(j&3)+8*(j>>2)+4h (+16 for frag b). A2 rows d>=3 are loaded as garbage
// (min(c,2) addressing, no branch) -- those D2 rows are never read.
// Staging layout, uniform 784B tile stride (branchless dual 8B loads):
//   tile t: [ half0 frags 32x16B | half1 compact 32x8B | const 8B | pad ]
// ws: stage 128*784=100,352B | A2 24,576B  -> 124,928 <= 128K (proven budget).

typedef short  bf16x8 __attribute__((ext_vector_type(8)));
typedef float  f32x16 __attribute__((ext_vector_type(16)));

#define K1f 1.4426950408889634f
#define K2f 2.8853900817779268f

constexpr int N_PTS  = 65536;
constexpr int FM     = 4096;
constexpr int SPLITS = 8;
constexpr int ETILES = FM / 32;          // 128 tiles
constexpr int TPS    = ETILES / SPLITS;  // 16 tiles per block
constexpr int TSTRIDE = 784;             // bytes per staged tile block
constexpr size_t A2_OFF = (size_t)ETILES * TSTRIDE;      // 100,352
// A2 size: 128*2*2*48B = 24,576 -> end 124,928

__device__ __forceinline__ unsigned short bf16r(float f) {   // RNE f32->bf16
  unsigned u = __float_as_uint(f);
  return (unsigned short)((u + 0x7FFFu + ((u >> 16) & 1u)) >> 16);
}
__device__ __forceinline__ float bf2f(unsigned short h) {
  return __uint_as_float(((unsigned)h) << 16);
}

union FragU { uint4 u4; bf16x8 bf; };

__global__ __launch_bounds__(256) void pack_kernel(
    const float* __restrict__ supp_pts, const float* __restrict__ supp_vec,
    const float* __restrict__ Cont, char* __restrict__ ws) {
  int e = blockIdx.x * blockDim.x + threadIdx.x;
  if (e >= FM) return;
  float sx = supp_pts[e * 3 + 0];
  float sy = supp_pts[e * 3 + 1];
  float sz = supp_pts[e * 3 + 2];
  float tx = K2f * sx, ty = K2f * sy, tz = K2f * sz;
  unsigned short shx = bf16r(tx), shy = bf16r(ty), shz = bf16r(tz);
  unsigned short slx = bf16r(tx - bf2f(shx));
  unsigned short sly = bf16r(ty - bf2f(shy));
  unsigned short slz = bf16r(tz - bf2f(shz));
  float ye = -K1f * (sx * sx + sy * sy + sz * sz);
  unsigned short yh = bf16r(ye);
  unsigned short yl = bf16r(ye - bf2f(yh));
  const unsigned short ONE = 0x3F80;    // bf16 1.0

  int t = e >> 5, c = e & 31;
  char* tb = ws + (size_t)t * TSTRIDE;
  // half0 fragment, 16B: [shx,shy,shz,shx,shy,shz,slx,sly]
  unsigned short* pa = (unsigned short*)(tb) + (size_t)c * 8;
  pa[0] = shx; pa[1] = shy; pa[2] = shz; pa[3] = shx;
  pa[4] = shy; pa[5] = shz; pa[6] = slx; pa[7] = sly;
  // half1 compact, 8B: [slz, yh, yl, 0]
  unsigned short* pb = (unsigned short*)(tb + 512) + (size_t)c * 4;
  pb[0] = slz; pb[1] = yh; pb[2] = yl; pb[3] = 0;
  // per-tile const pair, 8B: [ONE, ONE, 0, 0]
  if (c == 0) {
    unsigned short* pc = (unsigned short*)(tb + 768);
    pc[0] = ONE; pc[1] = ONE; pc[2] = 0; pc[3] = 0;
  }

  // A2: cv[d][e] at slot (t, frag, h, d, j), e = (j&3)+8*(j>>2)+4h+16*frag
  int f = e >> 9;
  float cf = Cont[f];
  unsigned short cv0 = bf16r(cf * supp_vec[e * 3 + 0]);
  unsigned short cv1 = bf16r(cf * supp_vec[e * 3 + 1]);
  unsigned short cv2 = bf16r(cf * supp_vec[e * 3 + 2]);
  int frag = (c >> 4) & 1, el16 = c & 15;
  int h = (el16 >> 2) & 1;
  int j = (el16 & 3) + 4 * (el16 >> 3);
  unsigned short* a2 = (unsigned short*)(ws + A2_OFF) +
                       (size_t)(((t * 2 + frag) * 2 + h) * 24 + j);
  a2[0] = cv0; a2[8] = cv1; a2[16] = cv2;   // row stride 8 slots
}

__global__ __launch_bounds__(256) void speed_kernel(
    const float* __restrict__ Points, const char* __restrict__ ws,
    float* __restrict__ out) {
  const int tid   = threadIdx.x;
  const int l     = tid & 63;
  const int wave  = tid >> 6;
  const int half  = l >> 5;
  const int c     = l & 31;
  const int split = blockIdx.x & (SPLITS - 1);
  const int nblk  = blockIdx.x / SPLITS;
  const int n_base = nblk * 128 + wave * 32;
  const int tbase  = split * TPS;

  // ---- point fragment (B operand of MFMA1) ----
  const int n = n_base + c;
  float x = Points[n * 3 + 0];
  float y = Points[n * 3 + 1];
  float z = Points[n * 3 + 2];
  float e1 = -K1f * (x * x + y * y + z * z);
  unsigned short qhx = bf16r(x), qhy = bf16r(y), qhz = bf16r(z);
  unsigned short qlx = bf16r(x - bf2f(qhx));
  unsigned short qly = bf16r(y - bf2f(qhy));
  unsigned short qlz = bf16r(z - bf2f(qhz));
  unsigned short xh  = bf16r(e1);
  unsigned short xl  = bf16r(e1 - bf2f(xh));
  const short ONE = (short)0x3F80;

  bf16x8 af;
  if (half == 0) {
    af = (bf16x8){(short)qhx, (short)qhy, (short)qhz, (short)qlx,
                  (short)qly, (short)qlz, (short)qhx, (short)qhy};
  } else {
    af = (bf16x8){(short)qhz, ONE, ONE, 0, (short)xh, (short)xl, 0, 0};
  }

  // ---- branchless per-lane staging pointers, uniform 784B tile stride ----
  const char* base = ws + (size_t)tbase * TSTRIDE;
  const char* pLo  = (half == 0) ? base + (size_t)c * 16
                                 : base + 512 + (size_t)c * 8;
  const char* pHi  = (half == 0) ? base + (size_t)c * 16 + 8
                                 : base + 768;
  const uint4* pA2 = (const uint4*)(ws + A2_OFF) +
                     ((size_t)tbase * 12 + half * 3 + (c < 2 ? c : 2));

  f32x16 acc2 = {};
  const f32x16 zc = {};

#define PACK2(r0, r1)                                                        \
  __builtin_amdgcn_perm(                                                     \
      __float_as_uint(__builtin_amdgcn_exp2f(D1[r1])),                       \
      __float_as_uint(__builtin_amdgcn_exp2f(D1[r0])), 0x07060302u)

#pragma unroll 4
  for (int t = 0; t < TPS; ++t) {
    uint2 lo = *(const uint2*)(pLo + (size_t)t * TSTRIDE);
    uint2 hi = *(const uint2*)(pHi + (size_t)t * TSTRIDE);
    FragU fa;  fa.u4  = make_uint4(lo.x, lo.y, hi.x, hi.y);
    FragU a2a; a2a.u4 = pA2[(size_t)t * 12];
    FragU a2b; a2b.u4 = pA2[(size_t)t * 12 + 6];

    f32x16 D1 = __builtin_amdgcn_mfma_f32_32x32x16_bf16(fa.bf, af, zc, 0, 0, 0);

    FragU b2a;
    b2a.u4 = make_uint4(PACK2(0, 1), PACK2(2, 3), PACK2(4, 5), PACK2(6, 7));
    acc2 = __builtin_amdgcn_mfma_f32_32x32x16_bf16(a2a.bf, b2a.bf, acc2, 0, 0, 0);

    FragU b2b;
    b2b.u4 = make_uint4(PACK2(8, 9), PACK2(10, 11), PACK2(12, 13), PACK2(14, 15));
    acc2 = __builtin_amdgcn_mfma_f32_32x32x16_bf16(a2b.bf, b2b.bf, acc2, 0, 0, 0);
  }
#undef PACK2

  // D2 rows 0..2 (= d) live at half 0, regs 0..2; col = n = lane&31.
  if (half == 0) {
    const int nn = n_base + c;
    unsafeAtomicAdd(&out[nn * 3 + 0], acc2[0]);
    unsafeAtomicAdd(&out[nn * 3 + 1], acc2[1]);
    unsafeAtomicAdd(&out[nn * 3 + 2], acc2[2]);
  }
}

extern "C" void kernel_launch(void* const* d_in, const int* in_sizes, int n_in,
                              void* d_out, int out_size, void* d_ws, size_t ws_size,
                              hipStream_t stream) {
  const float* Points   = (const float*)d_in[0];
  const float* supp_pts = (const float*)d_in[1];
  const float* supp_vec = (const float*)d_in[2];
  const float* Cont     = (const float*)d_in[3];
  float* out = (float*)d_out;
  char* ws = (char*)d_ws;    // 124,928 B used (<=128K proven budget)

  (void)hipMemsetAsync(d_out, 0, (size_t)out_size * sizeof(float), stream);
  pack_kernel<<<FM / 256, 256, 0, stream>>>(supp_pts, supp_vec, Cont, ws);
  speed_kernel<<<(N_PTS / 128) * SPLITS, 256, 0, stream>>>(Points, ws, out);
}